// Round 2
// baseline (2220.389 us; speedup 1.0000x reference)
//
#include <hip/hip_runtime.h>
#include <hip/hip_bf16.h>
#include <stdint.h>

// Shapes
#define NS 256   // seq (attended axis)
#define NL 384   // columns
#define NC 256   // channel
#define NH 8     // heads
#define ND 32    // head dim
#define NHD 256  // NH*ND
#define NFQ 0.17677669529663687f  // 1/sqrt(32)

typedef unsigned short u16;
typedef unsigned int u32;

__device__ __forceinline__ float bf2f(u16 u) {
  union { u32 u; float f; } w; w.u = ((u32)u) << 16; return w.f;
}
__device__ __forceinline__ float lo16(u32 u) {
  union { u32 u; float f; } w; w.u = u << 16; return w.f;
}
__device__ __forceinline__ float hi16(u32 u) {
  union { u32 u; float f; } w; w.u = u & 0xffff0000u; return w.f;
}
__device__ __forceinline__ u16 f2bf_rne(float f) {
  u32 x = __float_as_uint(f);
  u32 lsb = (x >> 16) & 1u;
  x += 0x7fffu + lsb;
  return (u16)(x >> 16);
}

// dtype-generic element load
template<bool F32>
__device__ __forceinline__ float ldE(const void* p, size_t i) {
  if constexpr (F32) return ((const float*)p)[i];
  else               return bf2f(((const u16*)p)[i]);
}
// dtype-generic 16-contiguous-element load (i must be multiple of 16)
template<bool F32>
__device__ __forceinline__ void ld16(const void* p, size_t i, float* x) {
  if constexpr (F32) {
    const float4* q = (const float4*)((const float*)p + i);
#pragma unroll
    for (int w = 0; w < 4; ++w) {
      float4 v = q[w];
      x[4*w] = v.x; x[4*w+1] = v.y; x[4*w+2] = v.z; x[4*w+3] = v.w;
    }
  } else {
    const uint4* q = (const uint4*)((const u16*)p + i);
#pragma unroll
    for (int w = 0; w < 2; ++w) {
      uint4 v = q[w];
      u32 uu[4] = {v.x, v.y, v.z, v.w};
#pragma unroll
      for (int pk = 0; pk < 4; ++pk) {
        x[8*w + 2*pk]     = lo16(uu[pk]);
        x[8*w + 2*pk + 1] = hi16(uu[pk]);
      }
    }
  }
}

// ---------------- dtype probe ----------------
// Reads first 256 u16 words of msa. bf16 N(0,1) data: ~all exponents in
// [100,150]. fp32 data read as u16: low halves have random exponents
// (~20% sane) -> count ~154. Threshold 220 separates by >14 sigma.
__global__ void k_probe(const u16* __restrict__ msa, int* __restrict__ flag) {
  const int t = threadIdx.x;  // 64 threads
  int cnt = 0;
#pragma unroll
  for (int i = 0; i < 4; ++i) {
    u16 v = msa[t * 4 + i];
    int e = (v >> 7) & 0xFF;
    cnt += (e >= 100 && e <= 150) ? 1 : 0;
  }
#pragma unroll
  for (int m = 1; m < 64; m <<= 1) cnt += __shfl_xor(cnt, m, 64);
  if (t == 0) *flag = (cnt < 220) ? 1 : 0;  // 1 = fp32 buffers
}

// ---------------- Kernel A: LayerNorm + q/k/v/gate projections ----------------
// 6144 blocks x 256 threads, 16 rows (s,l) per block.
// Outputs (always bf16) laid out [L][H][S][D].
template<bool F32>
__device__ __forceinline__ void ln_proj_body(
    const void* msa, const void* gamma_, const void* beta_,
    const void* wq, const void* wk, const void* wv, const void* wg,
    const void* bg, u16* qb, u16* kb, u16* vb, u16* gb,
    float (&mt)[NC][16]) {
  const int t = threadIdx.x;
  const int row0 = blockIdx.x * 16;

  {  // LayerNorm: 16 threads per row
    const int row = t >> 4;
    const int sub = t & 15;
    float x[16];
    ld16<F32>(msa, (size_t)(row0 + row) * NC + sub * 16, x);
    float s = 0.f, ss = 0.f;
#pragma unroll
    for (int i = 0; i < 16; ++i) { s += x[i]; ss += x[i] * x[i]; }
#pragma unroll
    for (int msk = 1; msk < 16; msk <<= 1) {
      s  += __shfl_xor(s,  msk, 64);
      ss += __shfl_xor(ss, msk, 64);
    }
    float mu  = s * (1.0f / NC);
    float var = fmaxf(ss * (1.0f / NC) - mu * mu, 0.0f);
    float rs  = rsqrtf(var + 1e-5f);
#pragma unroll
    for (int i = 0; i < 16; ++i) {
      float g  = ldE<F32>(gamma_, sub * 16 + i);
      float be = ldE<F32>(beta_,  sub * 16 + i);
      mt[sub * 16 + i][row] = (x[i] - mu) * rs * g + be;
    }
  }
  __syncthreads();

  // projections: thread t owns output column n for all 4 weights
  const int n = t;
  const int h = n >> 5, d = n & 31;
  float acc0[16], acc1[16], acc2[16], acc3[16];
#pragma unroll
  for (int r = 0; r < 16; ++r) { acc0[r]=0.f; acc1[r]=0.f; acc2[r]=0.f; acc3[r]=0.f; }

  for (int c = 0; c < NC; ++c) {
    float wqv = ldE<F32>(wq, (size_t)c * NHD + n);
    float wkv = ldE<F32>(wk, (size_t)c * NHD + n);
    float wvv = ldE<F32>(wv, (size_t)c * NHD + n);
    float wgv = ldE<F32>(wg, (size_t)c * NHD + n);
    const float4* mrow = (const float4*)&mt[c][0];  // uniform addr -> broadcast
    float4 m0 = mrow[0], m1 = mrow[1], m2 = mrow[2], m3 = mrow[3];
    float mm[16] = {m0.x, m0.y, m0.z, m0.w, m1.x, m1.y, m1.z, m1.w,
                    m2.x, m2.y, m2.z, m2.w, m3.x, m3.y, m3.z, m3.w};
#pragma unroll
    for (int r = 0; r < 16; ++r) {
      acc0[r] += mm[r] * wqv;
      acc1[r] += mm[r] * wkv;
      acc2[r] += mm[r] * wvv;
      acc3[r] += mm[r] * wgv;
    }
  }

  float bgv = ldE<F32>(bg, n);
  const int s0 = row0 / NL;   // 16 | 384 so the tile shares s
  const int l0 = row0 % NL;
#pragma unroll
  for (int r = 0; r < 16; ++r) {
    const int l = l0 + r;
    const size_t base = ((size_t)(l * NH + h) * NS + s0) * ND + d;
    qb[base] = f2bf_rne(acc0[r] * NFQ);
    kb[base] = f2bf_rne(acc1[r]);
    vb[base] = f2bf_rne(acc2[r]);
    float gz = acc3[r] + bgv;
    gb[base] = f2bf_rne(1.0f / (1.0f + __expf(-gz)));
  }
}

__launch_bounds__(256)
__global__ void k_ln_proj(const int* __restrict__ flag,
                          const void* __restrict__ msa,
                          const void* __restrict__ gamma_,
                          const void* __restrict__ beta_,
                          const void* __restrict__ wq,
                          const void* __restrict__ wk,
                          const void* __restrict__ wv,
                          const void* __restrict__ wg,
                          const void* __restrict__ bg,
                          u16* __restrict__ qb,
                          u16* __restrict__ kb,
                          u16* __restrict__ vb,
                          u16* __restrict__ gb) {
  __shared__ float mt[NC][16];
  if (*flag) ln_proj_body<true >(msa, gamma_, beta_, wq, wk, wv, wg, bg, qb, kb, vb, gb, mt);
  else       ln_proj_body<false>(msa, gamma_, beta_, wq, wk, wv, wg, bg, qb, kb, vb, gb, mt);
}

// ---------------- Kernel B: column attention per (c,h) ----------------
// Grid: L*H = 3072 blocks x 256 threads; thread i owns query row i.
__launch_bounds__(256)
__global__ void k_attn(const int* __restrict__ flag,
                       const u16* __restrict__ qb,
                       const u16* __restrict__ kb,
                       const u16* __restrict__ vb,
                       const u16* __restrict__ gb,
                       void* __restrict__ outp) {
  __shared__ uint4 ks4[1024];  // 256 x 32 bf16 = 16KB
  __shared__ uint4 vs4[1024];
  const int t = threadIdx.x;
  const int bid = blockIdx.x;           // c*8 + h
  const int c = bid >> 3, h = bid & 7;
  const size_t base = (size_t)bid * (NS * ND);  // elements

  const uint4* kg = (const uint4*)(kb + base);
  const uint4* vg = (const uint4*)(vb + base);
#pragma unroll
  for (int i = 0; i < 4; ++i) {
    ks4[t + 256 * i] = kg[t + 256 * i];
    vs4[t + 256 * i] = vg[t + 256 * i];
  }

  float qr[32];
  {
    const uint4* qg = (const uint4*)(qb + base + (size_t)t * ND);
#pragma unroll
    for (int w = 0; w < 4; ++w) {
      uint4 u = qg[w];
      u32 uu[4] = {u.x, u.y, u.z, u.w};
#pragma unroll
      for (int p = 0; p < 4; ++p) {
        qr[w*8 + 2*p]     = lo16(uu[p]);
        qr[w*8 + 2*p + 1] = hi16(uu[p]);
      }
    }
  }
  __syncthreads();

  float mrun = -1e30f, lrun = 0.f;
  float o[32];
#pragma unroll
  for (int d = 0; d < 32; ++d) o[d] = 0.f;

  for (int jc = 0; jc < 16; ++jc) {
    float sc[16];
#pragma unroll
    for (int jj = 0; jj < 16; ++jj) {
      const int j = jc * 16 + jj;
      float acc = 0.f;
#pragma unroll
      for (int w = 0; w < 4; ++w) {
        uint4 u = ks4[j * 4 + w];   // uniform addr -> broadcast
        u32 uu[4] = {u.x, u.y, u.z, u.w};
#pragma unroll
        for (int p = 0; p < 4; ++p) {
          acc += qr[w*8 + 2*p]     * lo16(uu[p]);
          acc += qr[w*8 + 2*p + 1] * hi16(uu[p]);
        }
      }
      sc[jj] = acc;
    }
    float cmax = sc[0];
#pragma unroll
    for (int jj = 1; jj < 16; ++jj) cmax = fmaxf(cmax, sc[jj]);
    float nm  = fmaxf(mrun, cmax);
    float fac = __expf(mrun - nm);
    lrun *= fac;
#pragma unroll
    for (int d = 0; d < 32; ++d) o[d] *= fac;
#pragma unroll
    for (int jj = 0; jj < 16; ++jj) {
      const int j = jc * 16 + jj;
      float p = __expf(sc[jj] - nm);
      lrun += p;
#pragma unroll
      for (int w = 0; w < 4; ++w) {
        uint4 u = vs4[j * 4 + w];
        u32 uu[4] = {u.x, u.y, u.z, u.w};
#pragma unroll
        for (int q = 0; q < 4; ++q) {
          o[w*8 + 2*q]     += p * lo16(uu[q]);
          o[w*8 + 2*q + 1] += p * hi16(uu[q]);
        }
      }
    }
    mrun = nm;
  }

  float inv = 1.0f / lrun;
  float gt[32];
  {
    const uint4* gg = (const uint4*)(gb + base + (size_t)t * ND);
#pragma unroll
    for (int w = 0; w < 4; ++w) {
      uint4 u = gg[w];
      u32 uu[4] = {u.x, u.y, u.z, u.w};
#pragma unroll
      for (int p = 0; p < 4; ++p) {
        gt[w*8 + 2*p]     = lo16(uu[p]);
        gt[w*8 + 2*p + 1] = hi16(uu[p]);
      }
    }
  }
  const size_t off = ((size_t)t * NL + c) * NHD + h * ND;
  if (*flag) {
    alignas(16) float rf[32];
#pragma unroll
    for (int d = 0; d < 32; ++d) rf[d] = o[d] * inv * gt[d];
    float4* ov = (float4*)((float*)outp + off);
    const float4* rv = (const float4*)rf;
#pragma unroll
    for (int w = 0; w < 8; ++w) ov[w] = rv[w];
  } else {
    alignas(16) u16 res[32];
#pragma unroll
    for (int d = 0; d < 32; ++d) res[d] = f2bf_rne(o[d] * inv * gt[d]);
    uint4* ov = (uint4*)((u16*)outp + off);
    const uint4* rv = (const uint4*)res;
#pragma unroll
    for (int w = 0; w < 4; ++w) ov[w] = rv[w];
  }
}

// ---------------- Kernel C: out = out_pre @ wo + bo (in-place on d_out) ----------------
template<bool F32>
__device__ __forceinline__ void out_body(void* io, const void* wo, const void* bo,
                                         float (&xt)[NHD][16]) {
  const int t = threadIdx.x;
  const int row0 = blockIdx.x * 16;
  {
    const int row = t >> 4, sub = t & 15;
    float x[16];
    ld16<F32>(io, (size_t)(row0 + row) * NHD + sub * 16, x);
#pragma unroll
    for (int i = 0; i < 16; ++i) xt[sub * 16 + i][row] = x[i];
  }
  __syncthreads();

  const int n = t;
  float acc[16];
#pragma unroll
  for (int r = 0; r < 16; ++r) acc[r] = 0.f;
  for (int c = 0; c < NHD; ++c) {
    float w = ldE<F32>(wo, (size_t)c * NC + n);
    const float4* mrow = (const float4*)&xt[c][0];
    float4 m0 = mrow[0], m1 = mrow[1], m2 = mrow[2], m3 = mrow[3];
    float mm[16] = {m0.x, m0.y, m0.z, m0.w, m1.x, m1.y, m1.z, m1.w,
                    m2.x, m2.y, m2.z, m2.w, m3.x, m3.y, m3.z, m3.w};
#pragma unroll
    for (int r = 0; r < 16; ++r) acc[r] += mm[r] * w;
  }
  float bov = ldE<F32>(bo, n);
#pragma unroll
  for (int r = 0; r < 16; ++r) {
    if constexpr (F32) ((float*)io)[(size_t)(row0 + r) * NC + n] = acc[r] + bov;
    else               ((u16*)io)[(size_t)(row0 + r) * NC + n] = f2bf_rne(acc[r] + bov);
  }
}

__launch_bounds__(256)
__global__ void k_out(const int* __restrict__ flag,
                      void* __restrict__ io,
                      const void* __restrict__ wo,
                      const void* __restrict__ bo) {
  __shared__ float xt[NHD][16];
  if (*flag) out_body<true >(io, wo, bo, xt);
  else       out_body<false>(io, wo, bo, xt);
}

extern "C" void kernel_launch(void* const* d_in, const int* in_sizes, int n_in,
                              void* d_out, int out_size, void* d_ws, size_t ws_size,
                              hipStream_t stream) {
  const void* msa    = d_in[0];
  const void* gamma_ = d_in[1];
  const void* beta_  = d_in[2];
  const void* wq     = d_in[3];
  const void* wk     = d_in[4];
  const void* wv     = d_in[5];
  const void* wg     = d_in[6];
  const void* bg     = d_in[7];
  const void* wo     = d_in[8];
  const void* bo     = d_in[9];

  const size_t NE = (size_t)NS * NL * NH * ND;  // 25,165,824 elems
  int* flag = (int*)d_ws;
  u16* qb = (u16*)((char*)d_ws + 256);  // 256B pad keeps buffers aligned
  u16* kb = qb + NE;
  u16* vb = kb + NE;
  u16* gb = vb + NE;

  k_probe<<<dim3(1), dim3(64), 0, stream>>>((const u16*)msa, flag);
  k_ln_proj<<<dim3(6144), dim3(256), 0, stream>>>(flag, msa, gamma_, beta_, wq, wk, wv, wg, bg,
                                                  qb, kb, vb, gb);
  k_attn<<<dim3(NL * NH), dim3(256), 0, stream>>>(flag, qb, kb, vb, gb, d_out);
  k_out<<<dim3(6144), dim3(256), 0, stream>>>(flag, d_out, wo, bo);
}

// Round 4
// 1117.448 us; speedup vs baseline: 1.9870x; 1.9870x over previous
//
#include <hip/hip_runtime.h>
#include <hip/hip_bf16.h>
#include <stdint.h>

// Shapes
#define NS 256   // seq (attended axis)
#define NL 384   // columns
#define NC 256   // channel
#define NH 8     // heads
#define ND 32    // head dim
#define NHD 256  // NH*ND
#define NFQ 0.17677669529663687f  // 1/sqrt(32)

typedef unsigned short u16;
typedef unsigned int u32;
typedef __attribute__((ext_vector_type(8))) short short8;
typedef __attribute__((ext_vector_type(4))) float f32x4;

__device__ __forceinline__ float bf2f(u16 u) {
  union { u32 u; float f; } w; w.u = ((u32)u) << 16; return w.f;
}
__device__ __forceinline__ float lo16(u32 u) {
  union { u32 u; float f; } w; w.u = u << 16; return w.f;
}
__device__ __forceinline__ float hi16(u32 u) {
  union { u32 u; float f; } w; w.u = u & 0xffff0000u; return w.f;
}
__device__ __forceinline__ u16 f2bf_rne(float f) {
  u32 x = __float_as_uint(f);
  u32 lsb = (x >> 16) & 1u;
  x += 0x7fffu + lsb;
  return (u16)(x >> 16);
}

// dtype-generic element load
template<bool F32>
__device__ __forceinline__ float ldE(const void* p, size_t i) {
  if constexpr (F32) return ((const float*)p)[i];
  else               return bf2f(((const u16*)p)[i]);
}
// dtype-generic 16-contiguous-element load (i must be multiple of 16)
template<bool F32>
__device__ __forceinline__ void ld16(const void* p, size_t i, float* x) {
  if constexpr (F32) {
    const float4* q = (const float4*)((const float*)p + i);
#pragma unroll
    for (int w = 0; w < 4; ++w) {
      float4 v = q[w];
      x[4*w] = v.x; x[4*w+1] = v.y; x[4*w+2] = v.z; x[4*w+3] = v.w;
    }
  } else {
    const uint4* q = (const uint4*)((const u16*)p + i);
#pragma unroll
    for (int w = 0; w < 2; ++w) {
      uint4 v = q[w];
      u32 uu[4] = {v.x, v.y, v.z, v.w};
#pragma unroll
      for (int pk = 0; pk < 4; ++pk) {
        x[8*w + 2*pk]     = lo16(uu[pk]);
        x[8*w + 2*pk + 1] = hi16(uu[pk]);
      }
    }
  }
}

// ---------------- dtype probe ----------------
__global__ void k_probe(const u16* __restrict__ msa, int* __restrict__ flag) {
  const int t = threadIdx.x;  // 64 threads
  int cnt = 0;
#pragma unroll
  for (int i = 0; i < 4; ++i) {
    u16 v = msa[t * 4 + i];
    int e = (v >> 7) & 0xFF;
    cnt += (e >= 100 && e <= 150) ? 1 : 0;
  }
#pragma unroll
  for (int m = 1; m < 64; m <<= 1) cnt += __shfl_xor(cnt, m, 64);
  if (t == 0) *flag = (cnt < 220) ? 1 : 0;  // 1 = fp32 buffers
}

// ---------------- Kernel A: LayerNorm + q/k/v/gate projections ----------------
template<bool F32>
__device__ __forceinline__ void ln_proj_body(
    const void* msa, const void* gamma_, const void* beta_,
    const void* wq, const void* wk, const void* wv, const void* wg,
    const void* bg, u16* qb, u16* kb, u16* vb, u16* gb,
    float (&mt)[NC][16]) {
  const int t = threadIdx.x;
  const int row0 = blockIdx.x * 16;

  {  // LayerNorm: 16 threads per row
    const int row = t >> 4;
    const int sub = t & 15;
    float x[16];
    ld16<F32>(msa, (size_t)(row0 + row) * NC + sub * 16, x);
    float s = 0.f, ss = 0.f;
#pragma unroll
    for (int i = 0; i < 16; ++i) { s += x[i]; ss += x[i] * x[i]; }
#pragma unroll
    for (int msk = 1; msk < 16; msk <<= 1) {
      s  += __shfl_xor(s,  msk, 64);
      ss += __shfl_xor(ss, msk, 64);
    }
    float mu  = s * (1.0f / NC);
    float var = fmaxf(ss * (1.0f / NC) - mu * mu, 0.0f);
    float rs  = rsqrtf(var + 1e-5f);
#pragma unroll
    for (int i = 0; i < 16; ++i) {
      float g  = ldE<F32>(gamma_, sub * 16 + i);
      float be = ldE<F32>(beta_,  sub * 16 + i);
      mt[sub * 16 + i][row] = (x[i] - mu) * rs * g + be;
    }
  }
  __syncthreads();

  const int n = t;
  const int h = n >> 5, d = n & 31;
  float acc0[16], acc1[16], acc2[16], acc3[16];
#pragma unroll
  for (int r = 0; r < 16; ++r) { acc0[r]=0.f; acc1[r]=0.f; acc2[r]=0.f; acc3[r]=0.f; }

  for (int c = 0; c < NC; ++c) {
    float wqv = ldE<F32>(wq, (size_t)c * NHD + n);
    float wkv = ldE<F32>(wk, (size_t)c * NHD + n);
    float wvv = ldE<F32>(wv, (size_t)c * NHD + n);
    float wgv = ldE<F32>(wg, (size_t)c * NHD + n);
    const float4* mrow = (const float4*)&mt[c][0];
    float4 m0 = mrow[0], m1 = mrow[1], m2 = mrow[2], m3 = mrow[3];
    float mm[16] = {m0.x, m0.y, m0.z, m0.w, m1.x, m1.y, m1.z, m1.w,
                    m2.x, m2.y, m2.z, m2.w, m3.x, m3.y, m3.z, m3.w};
#pragma unroll
    for (int r = 0; r < 16; ++r) {
      acc0[r] += mm[r] * wqv;
      acc1[r] += mm[r] * wkv;
      acc2[r] += mm[r] * wvv;
      acc3[r] += mm[r] * wgv;
    }
  }

  float bgv = ldE<F32>(bg, n);
  const int s0 = row0 / NL;
  const int l0 = row0 % NL;
#pragma unroll
  for (int r = 0; r < 16; ++r) {
    const int l = l0 + r;
    const size_t base = ((size_t)(l * NH + h) * NS + s0) * ND + d;
    qb[base] = f2bf_rne(acc0[r] * NFQ);
    kb[base] = f2bf_rne(acc1[r]);
    vb[base] = f2bf_rne(acc2[r]);
    float gz = acc3[r] + bgv;
    gb[base] = f2bf_rne(1.0f / (1.0f + __expf(-gz)));
  }
}

__launch_bounds__(256)
__global__ void k_ln_proj(const int* __restrict__ flag,
                          const void* __restrict__ msa,
                          const void* __restrict__ gamma_,
                          const void* __restrict__ beta_,
                          const void* __restrict__ wq,
                          const void* __restrict__ wk,
                          const void* __restrict__ wv,
                          const void* __restrict__ wg,
                          const void* __restrict__ bg,
                          u16* __restrict__ qb,
                          u16* __restrict__ kb,
                          u16* __restrict__ vb,
                          u16* __restrict__ gb) {
  __shared__ float mt[NC][16];
  if (*flag) ln_proj_body<true >(msa, gamma_, beta_, wq, wk, wv, wg, bg, qb, kb, vb, gb, mt);
  else       ln_proj_body<false>(msa, gamma_, beta_, wq, wk, wv, wg, bg, qb, kb, vb, gb, mt);
}

// ---------------- Kernel B: MFMA column attention per (c,h) ----------------
// 3072 blocks x 256 threads (4 waves); wave w owns q rows [64w, 64w+64).
// Per 16-row q-tile: swapped QK^T (S^T via mfma(K,Q)) -> exact softmax in
// regs -> normalized P (bf16) -> LDS -> direct PV mfma.
#define PPAD 264  // 256 + 8 elements: uniform LDS bank spread for b128 reads

__launch_bounds__(256)
__global__ void k_attn(const int* __restrict__ flag,
                       const u16* __restrict__ qb,
                       const u16* __restrict__ kb,
                       const u16* __restrict__ vb,
                       const u16* __restrict__ gb,
                       void* __restrict__ outp) {
  __shared__ u16 Ks[NS * ND];        // [key][d] 16KB
  __shared__ u16 Vs[NS * ND];        // [key][d] 16KB
  __shared__ u16 Ps[4][16 * PPAD];   // per-wave P [q][key], padded, 33KB
  const int t = threadIdx.x;
  const int w = t >> 6;
  const int lane = t & 63;
  const int q15 = lane & 15;
  const int g = lane >> 4;
  const int bid = blockIdx.x;        // c*8 + h
  const int c = bid >> 3, h = bid & 7;
  const size_t base = (size_t)bid * (NS * ND);
  const bool isf32 = (*flag != 0);

  // stage K, V: 1024 uint4 each (R3 bug: only 512 were staged -> NaN)
  {
    const uint4* kg = (const uint4*)(kb + base);
    const uint4* vg = (const uint4*)(vb + base);
    uint4* ksv = (uint4*)Ks;
    uint4* vsv = (uint4*)Vs;
#pragma unroll
    for (int i = 0; i < 4; ++i) {
      ksv[t + 256 * i] = kg[t + 256 * i];
      vsv[t + 256 * i] = vg[t + 256 * i];
    }
  }

  // Q fragments for this wave's 4 q-tiles (B-operand of swapped QK^T):
  // lane: col=q=q15, k = g*8+j -> 8 contiguous bf16 of Q[q][.]
  short8 qf[4];
  const int q0w = w * 64;
#pragma unroll
  for (int it = 0; it < 4; ++it) {
    union { uint4 u; short8 s; } cv;
    cv.u = *(const uint4*)(qb + base + (size_t)(q0w + it * 16 + q15) * ND + g * 8);
    qf[it] = cv.s;
  }
  __syncthreads();

  // V fragments (B-operand of PV): lane: col=d=q15+16*dt, k=g*8+j ->
  // V[kc*32+g*8+j][d], gathered once per wave (scalar LDS reads).
  short8 vf[2][8];
#pragma unroll
  for (int kc = 0; kc < 8; ++kc) {
#pragma unroll
    for (int dt = 0; dt < 2; ++dt) {
      union { u16 e[8]; short8 s; } cv;
#pragma unroll
      for (int j = 0; j < 8; ++j)
        cv.e[j] = Vs[(size_t)(kc * 32 + g * 8 + j) * ND + dt * 16 + q15];
      vf[dt][kc] = cv.s;
    }
  }

  u16* Pw = &Ps[w][0];
  const f32x4 zero = {0.f, 0.f, 0.f, 0.f};

  for (int it = 0; it < 4; ++it) {
    // ---- QK^T (swapped): D = K_tile * Q_tile^T -> S^T[key][q] ----
    f32x4 sc[16];
#pragma unroll
    for (int jt = 0; jt < 16; ++jt) {
      union { uint4 u; short8 s; } kf;
      kf.u = *(const uint4*)(Ks + (size_t)(jt * 16 + q15) * ND + g * 8);
      sc[jt] = __builtin_amdgcn_mfma_f32_16x16x32_bf16(kf.s, qf[it], zero, 0, 0, 0);
    }
    // lane holds 64 scores for q = q0w+it*16+q15: key = jt*16 + 4g + r
    float mx = sc[0][0];
#pragma unroll
    for (int jt = 0; jt < 16; ++jt)
#pragma unroll
      for (int r = 0; r < 4; ++r) mx = fmaxf(mx, sc[jt][r]);
    mx = fmaxf(mx, __shfl_xor(mx, 16, 64));
    mx = fmaxf(mx, __shfl_xor(mx, 32, 64));
    float sum = 0.f;
#pragma unroll
    for (int jt = 0; jt < 16; ++jt)
#pragma unroll
      for (int r = 0; r < 4; ++r) {
        float e = __expf(sc[jt][r] - mx);
        sc[jt][r] = e;
        sum += e;
      }
    sum += __shfl_xor(sum, 16, 64);
    sum += __shfl_xor(sum, 32, 64);
    float inv = 1.0f / sum;

    __syncthreads();  // previous-iteration P reads complete before overwrite
    // write normalized P (bf16) to LDS [q][key]
    {
      u16* pr = Pw + q15 * PPAD + 4 * g;
#pragma unroll
      for (int jt = 0; jt < 16; ++jt) {
        u32 lo = (u32)f2bf_rne(sc[jt][0] * inv) | ((u32)f2bf_rne(sc[jt][1] * inv) << 16);
        u32 hi = (u32)f2bf_rne(sc[jt][2] * inv) | ((u32)f2bf_rne(sc[jt][3] * inv) << 16);
        uint2 pk; pk.x = lo; pk.y = hi;
        *(uint2*)(pr + jt * 16) = pk;
      }
    }
    __syncthreads();  // P visible before fragment reads

    // ---- PV: D[q][d] = P[16q x 256k] @ V[256k x 32d] ----
    f32x4 o0 = zero, o1 = zero;
#pragma unroll
    for (int kc = 0; kc < 8; ++kc) {
      union { uint4 u; short8 s; } pa;
      pa.u = *(const uint4*)(Pw + q15 * PPAD + kc * 32 + g * 8);
      o0 = __builtin_amdgcn_mfma_f32_16x16x32_bf16(pa.s, vf[0][kc], o0, 0, 0, 0);
      o1 = __builtin_amdgcn_mfma_f32_16x16x32_bf16(pa.s, vf[1][kc], o1, 0, 0, 0);
    }

    // ---- epilogue: gate + store. lane: d = q15 (+16), q = it*16+4g+r ----
    const int qrow0 = q0w + it * 16 + 4 * g;
#pragma unroll
    for (int r = 0; r < 4; ++r) {
      const int s_idx = qrow0 + r;
      float g0 = bf2f(gb[base + (size_t)s_idx * ND + q15]);
      float g1 = bf2f(gb[base + (size_t)s_idx * ND + 16 + q15]);
      float r0 = o0[r] * g0;
      float r1 = o1[r] * g1;
      const size_t off = ((size_t)s_idx * NL + c) * NHD + h * ND;
      if (isf32) {
        ((float*)outp)[off + q15] = r0;
        ((float*)outp)[off + 16 + q15] = r1;
      } else {
        ((u16*)outp)[off + q15] = f2bf_rne(r0);
        ((u16*)outp)[off + 16 + q15] = f2bf_rne(r1);
      }
    }
  }
}

// ---------------- Kernel C: out = out_pre @ wo + bo (in-place on d_out) ----------------
template<bool F32>
__device__ __forceinline__ void out_body(void* io, const void* wo, const void* bo,
                                         float (&xt)[NHD][16]) {
  const int t = threadIdx.x;
  const int row0 = blockIdx.x * 16;
  {
    const int row = t >> 4, sub = t & 15;
    float x[16];
    ld16<F32>(io, (size_t)(row0 + row) * NHD + sub * 16, x);
#pragma unroll
    for (int i = 0; i < 16; ++i) xt[sub * 16 + i][row] = x[i];
  }
  __syncthreads();

  const int n = t;
  float acc[16];
#pragma unroll
  for (int r = 0; r < 16; ++r) acc[r] = 0.f;
  for (int c = 0; c < NHD; ++c) {
    float w = ldE<F32>(wo, (size_t)c * NC + n);
    const float4* mrow = (const float4*)&xt[c][0];
    float4 m0 = mrow[0], m1 = mrow[1], m2 = mrow[2], m3 = mrow[3];
    float mm[16] = {m0.x, m0.y, m0.z, m0.w, m1.x, m1.y, m1.z, m1.w,
                    m2.x, m2.y, m2.z, m2.w, m3.x, m3.y, m3.z, m3.w};
#pragma unroll
    for (int r = 0; r < 16; ++r) acc[r] += mm[r] * w;
  }
  float bov = ldE<F32>(bo, n);
#pragma unroll
  for (int r = 0; r < 16; ++r) {
    if constexpr (F32) ((float*)io)[(size_t)(row0 + r) * NC + n] = acc[r] + bov;
    else               ((u16*)io)[(size_t)(row0 + r) * NC + n] = f2bf_rne(acc[r] + bov);
  }
}

__launch_bounds__(256)
__global__ void k_out(const int* __restrict__ flag,
                      void* __restrict__ io,
                      const void* __restrict__ wo,
                      const void* __restrict__ bo) {
  __shared__ float xt[NHD][16];
  if (*flag) out_body<true >(io, wo, bo, xt);
  else       out_body<false>(io, wo, bo, xt);
}

extern "C" void kernel_launch(void* const* d_in, const int* in_sizes, int n_in,
                              void* d_out, int out_size, void* d_ws, size_t ws_size,
                              hipStream_t stream) {
  const void* msa    = d_in[0];
  const void* gamma_ = d_in[1];
  const void* beta_  = d_in[2];
  const void* wq     = d_in[3];
  const void* wk     = d_in[4];
  const void* wv     = d_in[5];
  const void* wg     = d_in[6];
  const void* bg     = d_in[7];
  const void* wo     = d_in[8];
  const void* bo     = d_in[9];

  const size_t NE = (size_t)NS * NL * NH * ND;  // 25,165,824 elems
  int* flag = (int*)d_ws;
  u16* qb = (u16*)((char*)d_ws + 256);
  u16* kb = qb + NE;
  u16* vb = kb + NE;
  u16* gb = vb + NE;

  k_probe<<<dim3(1), dim3(64), 0, stream>>>((const u16*)msa, flag);
  k_ln_proj<<<dim3(6144), dim3(256), 0, stream>>>(flag, msa, gamma_, beta_, wq, wk, wv, wg, bg,
                                                  qb, kb, vb, gb);
  k_attn<<<dim3(NL * NH), dim3(256), 0, stream>>>(flag, qb, kb, vb, gb, d_out);
  k_out<<<dim3(6144), dim3(256), 0, stream>>>(flag, d_out, wo, bo);
}

// Round 5
// 615.274 us; speedup vs baseline: 3.6088x; 1.8162x over previous
//
#include <hip/hip_runtime.h>
#include <hip/hip_bf16.h>
#include <stdint.h>

// Shapes
#define NS 256   // seq (attended axis)
#define NL 384   // columns
#define NC 256   // channel
#define NH 8     // heads
#define ND 32    // head dim
#define NHD 256  // NH*ND
#define NFQ 0.17677669529663687f  // 1/sqrt(32)

typedef unsigned short u16;
typedef unsigned int u32;
typedef __attribute__((ext_vector_type(8))) short short8;
typedef __attribute__((ext_vector_type(4))) float f32x4;

__device__ __forceinline__ float bf2f(u16 u) {
  union { u32 u; float f; } w; w.u = ((u32)u) << 16; return w.f;
}
__device__ __forceinline__ float lo16(u32 u) {
  union { u32 u; float f; } w; w.u = u << 16; return w.f;
}
__device__ __forceinline__ float hi16(u32 u) {
  union { u32 u; float f; } w; w.u = u & 0xffff0000u; return w.f;
}
__device__ __forceinline__ u16 f2bf_rne(float f) {
  u32 x = __float_as_uint(f);
  u32 lsb = (x >> 16) & 1u;
  x += 0x7fffu + lsb;
  return (u16)(x >> 16);
}
__device__ __forceinline__ u32 pk2(float a, float b) {
  return (u32)f2bf_rne(a) | ((u32)f2bf_rne(b) << 16);
}

// dtype-generic element load
template<bool F32>
__device__ __forceinline__ float ldE(const void* p, size_t i) {
  if constexpr (F32) return ((const float*)p)[i];
  else               return bf2f(((const u16*)p)[i]);
}
// dtype-generic 16-contiguous-element load (i must be multiple of 16)
template<bool F32>
__device__ __forceinline__ void ld16(const void* p, size_t i, float* x) {
  if constexpr (F32) {
    const float4* q = (const float4*)((const float*)p + i);
#pragma unroll
    for (int w = 0; w < 4; ++w) {
      float4 v = q[w];
      x[4*w] = v.x; x[4*w+1] = v.y; x[4*w+2] = v.z; x[4*w+3] = v.w;
    }
  } else {
    const uint4* q = (const uint4*)((const u16*)p + i);
#pragma unroll
    for (int w = 0; w < 2; ++w) {
      uint4 v = q[w];
      u32 uu[4] = {v.x, v.y, v.z, v.w};
#pragma unroll
      for (int pk = 0; pk < 4; ++pk) {
        x[8*w + 2*pk]     = lo16(uu[pk]);
        x[8*w + 2*pk + 1] = hi16(uu[pk]);
      }
    }
  }
}

// ---------------- dtype probe ----------------
__global__ void k_probe(const u16* __restrict__ msa, int* __restrict__ flag) {
  const int t = threadIdx.x;  // 64 threads
  int cnt = 0;
#pragma unroll
  for (int i = 0; i < 4; ++i) {
    u16 v = msa[t * 4 + i];
    int e = (v >> 7) & 0xFF;
    cnt += (e >= 100 && e <= 150) ? 1 : 0;
  }
#pragma unroll
  for (int m = 1; m < 64; m <<= 1) cnt += __shfl_xor(cnt, m, 64);
  if (t == 0) *flag = (cnt < 220) ? 1 : 0;  // 1 = fp32 buffers
}

// ---------------- k_wt: transpose+cast 5 weights to bf16 wT[n][k] ----------------
// grid 80 blocks: widx = b>>4 (wq,wk,wv,wg,wo), 16 tiles of 64x64 each.
__launch_bounds__(256)
__global__ void k_wt(const int* __restrict__ flag,
                     const void* __restrict__ w0, const void* __restrict__ w1,
                     const void* __restrict__ w2, const void* __restrict__ w3,
                     const void* __restrict__ w4,
                     u16* __restrict__ wT) {
  __shared__ float f[64][65];
  const int b = blockIdx.x;
  const int widx = b >> 4, tile = b & 15;
  const int k0 = (tile >> 2) * 64, n0 = (tile & 3) * 64;
  const void* src = widx == 0 ? w0 : widx == 1 ? w1 : widx == 2 ? w2 : widx == 3 ? w3 : w4;
  u16* dst = wT + widx * 65536;
  const int t = threadIdx.x;
  const bool isf32 = (*flag != 0);

  {  // read W[k][n] rows coalesced
    const int kr = t >> 2, nc = (t & 3) * 16;
    float x[16];
    if (isf32) ld16<true >(src, (size_t)(k0 + kr) * NHD + n0 + nc, x);
    else       ld16<false>(src, (size_t)(k0 + kr) * NHD + n0 + nc, x);
#pragma unroll
    for (int i = 0; i < 16; ++i) f[kr][nc + i] = x[i];
  }
  __syncthreads();
  {  // write wT[n][k] rows coalesced
    const int nr = t >> 2, kc = (t & 3) * 16;
    u32 pk[8];
#pragma unroll
    for (int i = 0; i < 8; ++i)
      pk[i] = pk2(f[kc + 2*i][nr], f[kc + 2*i + 1][nr]);
    uint4* dp = (uint4*)(dst + (size_t)(n0 + nr) * NC + k0 + kc);
    dp[0] = make_uint4(pk[0], pk[1], pk[2], pk[3]);
    dp[1] = make_uint4(pk[4], pk[5], pk[6], pk[7]);
  }
}

// ---------------- k_proj: fused LN + 4 projections via MFMA ----------------
// 1536 blocks x 256 threads. Block: 64 rows (one s, 64 consecutive l).
// LN -> bf16 A-tile in LDS (XOR-swizzled 16B slots). Wave w computes weight w
// (all 256 n) for all 64 rows. Epilogue fuses NFQ / sigmoid, scatters to
// [L][H][S][D].
__launch_bounds__(256)
__global__ void k_proj(const int* __restrict__ flag,
                       const void* __restrict__ msa,
                       const void* __restrict__ gamma_,
                       const void* __restrict__ beta_,
                       const void* __restrict__ bg,
                       const u16* __restrict__ wT,
                       u16* __restrict__ qb,
                       u16* __restrict__ kb,
                       u16* __restrict__ vb,
                       u16* __restrict__ gb) {
  __shared__ u16 As[64 * 256];  // 32 KB, 16B slot s' = s ^ (row&7)
  const int t = threadIdx.x;
  const int w = t >> 6;
  const int lane = t & 63;
  const int q15 = lane & 15;
  const int g = lane >> 4;
  const int row0 = blockIdx.x * 64;
  const int s = row0 / NL;
  const int l0 = row0 % NL;
  const bool isf32 = (*flag != 0);

  // ---- LN: 4 passes x 16 rows; 16 threads per row ----
#pragma unroll
  for (int p = 0; p < 4; ++p) {
    const int row = p * 16 + (t >> 4);
    const int sub = t & 15;
    float x[16];
    if (isf32) ld16<true >(msa, (size_t)(row0 + row) * NC + sub * 16, x);
    else       ld16<false>(msa, (size_t)(row0 + row) * NC + sub * 16, x);
    float sm = 0.f, ss = 0.f;
#pragma unroll
    for (int i = 0; i < 16; ++i) { sm += x[i]; ss += x[i] * x[i]; }
#pragma unroll
    for (int msk = 1; msk < 16; msk <<= 1) {
      sm += __shfl_xor(sm, msk, 64);
      ss += __shfl_xor(ss, msk, 64);
    }
    float mu  = sm * (1.0f / NC);
    float var = fmaxf(ss * (1.0f / NC) - mu * mu, 0.0f);
    float rs  = rsqrtf(var + 1e-5f);
    float y[16];
#pragma unroll
    for (int i = 0; i < 16; ++i) {
      float gm = isf32 ? ldE<true>(gamma_, sub * 16 + i) : ldE<false>(gamma_, sub * 16 + i);
      float be = isf32 ? ldE<true>(beta_,  sub * 16 + i) : ldE<false>(beta_,  sub * 16 + i);
      y[i] = (x[i] - mu) * rs * gm + be;
    }
    // two 16B slots: k16 = 2sub, 2sub+1, swizzled by row&7
#pragma unroll
    for (int j = 0; j < 2; ++j) {
      const int slot = (2 * sub + j) ^ (row & 7);
      uint4 pk = make_uint4(pk2(y[8*j+0], y[8*j+1]), pk2(y[8*j+2], y[8*j+3]),
                            pk2(y[8*j+4], y[8*j+5]), pk2(y[8*j+6], y[8*j+7]));
      *(uint4*)(As + (size_t)row * 256 + slot * 8) = pk;
    }
  }
  __syncthreads();

  // ---- MFMA: wave w -> weight w ----
  const u16* wTw = wT + (size_t)w * 65536;
  const f32x4 zero = {0.f, 0.f, 0.f, 0.f};

  for (int nt = 0; nt < 16; ++nt) {
    union { uint4 u; short8 s; } wf[8];
#pragma unroll
    for (int k8 = 0; k8 < 8; ++k8)
      wf[k8].u = *(const uint4*)(wTw + (size_t)(nt * 16 + q15) * NC + k8 * 32 + g * 8);
#pragma unroll
    for (int ms = 0; ms < 4; ++ms) {
      const int mi = ms * 16 + q15;
      f32x4 acc = zero;
#pragma unroll
      for (int k8 = 0; k8 < 8; ++k8) {
        const int slot = (k8 * 4 + g) ^ (mi & 7);
        union { uint4 u; short8 s; } af;
        af.u = *(const uint4*)(As + (size_t)mi * 256 + slot * 8);
        acc = __builtin_amdgcn_mfma_f32_16x16x32_bf16(wf[k8].s, af.s, acc, 0, 0, 0);
      }
      // epilogue: lane col = m (q15), rows n = nt*16 + 4g + r
      const int nl0 = nt * 16 + 4 * g;
      const int hh = nl0 >> 5, dd = nl0 & 31;
      const int l = l0 + ms * 16 + q15;
      const size_t ob = ((size_t)(l * NH + hh) * NS + s) * ND + dd;
      uint2 pk;
      if (w == 0) {
        pk.x = pk2(acc[0] * NFQ, acc[1] * NFQ);
        pk.y = pk2(acc[2] * NFQ, acc[3] * NFQ);
        *(uint2*)(qb + ob) = pk;
      } else if (w == 1) {
        pk.x = pk2(acc[0], acc[1]); pk.y = pk2(acc[2], acc[3]);
        *(uint2*)(kb + ob) = pk;
      } else if (w == 2) {
        pk.x = pk2(acc[0], acc[1]); pk.y = pk2(acc[2], acc[3]);
        *(uint2*)(vb + ob) = pk;
      } else {
        float z[4];
#pragma unroll
        for (int r = 0; r < 4; ++r) {
          float bgl = isf32 ? ldE<true>(bg, nl0 + r) : ldE<false>(bg, nl0 + r);
          z[r] = 1.0f / (1.0f + __expf(-(acc[r] + bgl)));
        }
        pk.x = pk2(z[0], z[1]); pk.y = pk2(z[2], z[3]);
        *(uint2*)(gb + ob) = pk;
      }
    }
  }
}

// ---------------- Kernel B: MFMA column attention per (c,h) ----------------
// (unchanged from R4 working version)
#define PPAD 264

__launch_bounds__(256)
__global__ void k_attn(const int* __restrict__ flag,
                       const u16* __restrict__ qb,
                       const u16* __restrict__ kb,
                       const u16* __restrict__ vb,
                       const u16* __restrict__ gb,
                       void* __restrict__ outp) {
  __shared__ u16 Ks[NS * ND];
  __shared__ u16 Vs[NS * ND];
  __shared__ u16 Ps[4][16 * PPAD];
  const int t = threadIdx.x;
  const int w = t >> 6;
  const int lane = t & 63;
  const int q15 = lane & 15;
  const int g = lane >> 4;
  const int bid = blockIdx.x;
  const int c = bid >> 3, h = bid & 7;
  const size_t base = (size_t)bid * (NS * ND);
  const bool isf32 = (*flag != 0);

  {
    const uint4* kg = (const uint4*)(kb + base);
    const uint4* vg = (const uint4*)(vb + base);
    uint4* ksv = (uint4*)Ks;
    uint4* vsv = (uint4*)Vs;
#pragma unroll
    for (int i = 0; i < 4; ++i) {
      ksv[t + 256 * i] = kg[t + 256 * i];
      vsv[t + 256 * i] = vg[t + 256 * i];
    }
  }

  short8 qf[4];
  const int q0w = w * 64;
#pragma unroll
  for (int it = 0; it < 4; ++it) {
    union { uint4 u; short8 s; } cv;
    cv.u = *(const uint4*)(qb + base + (size_t)(q0w + it * 16 + q15) * ND + g * 8);
    qf[it] = cv.s;
  }
  __syncthreads();

  short8 vf[2][8];
#pragma unroll
  for (int kc = 0; kc < 8; ++kc) {
#pragma unroll
    for (int dt = 0; dt < 2; ++dt) {
      union { u16 e[8]; short8 s; } cv;
#pragma unroll
      for (int j = 0; j < 8; ++j)
        cv.e[j] = Vs[(size_t)(kc * 32 + g * 8 + j) * ND + dt * 16 + q15];
      vf[dt][kc] = cv.s;
    }
  }

  u16* Pw = &Ps[w][0];
  const f32x4 zero = {0.f, 0.f, 0.f, 0.f};

  for (int it = 0; it < 4; ++it) {
    f32x4 sc[16];
#pragma unroll
    for (int jt = 0; jt < 16; ++jt) {
      union { uint4 u; short8 s; } kf;
      kf.u = *(const uint4*)(Ks + (size_t)(jt * 16 + q15) * ND + g * 8);
      sc[jt] = __builtin_amdgcn_mfma_f32_16x16x32_bf16(kf.s, qf[it], zero, 0, 0, 0);
    }
    float mx = sc[0][0];
#pragma unroll
    for (int jt = 0; jt < 16; ++jt)
#pragma unroll
      for (int r = 0; r < 4; ++r) mx = fmaxf(mx, sc[jt][r]);
    mx = fmaxf(mx, __shfl_xor(mx, 16, 64));
    mx = fmaxf(mx, __shfl_xor(mx, 32, 64));
    float sum = 0.f;
#pragma unroll
    for (int jt = 0; jt < 16; ++jt)
#pragma unroll
      for (int r = 0; r < 4; ++r) {
        float e = __expf(sc[jt][r] - mx);
        sc[jt][r] = e;
        sum += e;
      }
    sum += __shfl_xor(sum, 16, 64);
    sum += __shfl_xor(sum, 32, 64);
    float inv = 1.0f / sum;

    __syncthreads();
    {
      u16* pr = Pw + q15 * PPAD + 4 * g;
#pragma unroll
      for (int jt = 0; jt < 16; ++jt) {
        uint2 pk;
        pk.x = pk2(sc[jt][0] * inv, sc[jt][1] * inv);
        pk.y = pk2(sc[jt][2] * inv, sc[jt][3] * inv);
        *(uint2*)(pr + jt * 16) = pk;
      }
    }
    __syncthreads();

    f32x4 o0 = zero, o1 = zero;
#pragma unroll
    for (int kc = 0; kc < 8; ++kc) {
      union { uint4 u; short8 s; } pa;
      pa.u = *(const uint4*)(Pw + q15 * PPAD + kc * 32 + g * 8);
      o0 = __builtin_amdgcn_mfma_f32_16x16x32_bf16(pa.s, vf[0][kc], o0, 0, 0, 0);
      o1 = __builtin_amdgcn_mfma_f32_16x16x32_bf16(pa.s, vf[1][kc], o1, 0, 0, 0);
    }

    const int qrow0 = q0w + it * 16 + 4 * g;
#pragma unroll
    for (int r = 0; r < 4; ++r) {
      const int s_idx = qrow0 + r;
      float g0 = bf2f(gb[base + (size_t)s_idx * ND + q15]);
      float g1 = bf2f(gb[base + (size_t)s_idx * ND + 16 + q15]);
      float r0 = o0[r] * g0;
      float r1 = o1[r] * g1;
      const size_t off = ((size_t)s_idx * NL + c) * NHD + h * ND;
      if (isf32) {
        ((float*)outp)[off + q15] = r0;
        ((float*)outp)[off + 16 + q15] = r1;
      } else {
        ((u16*)outp)[off + q15] = f2bf_rne(r0);
        ((u16*)outp)[off + 16 + q15] = f2bf_rne(r1);
      }
    }
  }
}

// ---------------- k_out: MFMA out-projection, in-place on d_out ----------------
// 1536 blocks. Stage 64 rows of d_out (attn out) -> bf16 swizzled LDS, then
// wave w computes n in [64w, 64w+64) with woT frags; += bo; store.
__launch_bounds__(256)
__global__ void k_out(const int* __restrict__ flag,
                      void* __restrict__ io,
                      const u16* __restrict__ woT,
                      const void* __restrict__ bo) {
  __shared__ u16 As[64 * 256];  // 32 KB swizzled
  const int t = threadIdx.x;
  const int w = t >> 6;
  const int lane = t & 63;
  const int q15 = lane & 15;
  const int g = lane >> 4;
  const int row0 = blockIdx.x * 64;
  const bool isf32 = (*flag != 0);

  {  // stage + convert: thread t: row = t>>2, 64-elem quarter q4 = t&3
    const int row = t >> 2, q4 = t & 3;
#pragma unroll
    for (int i = 0; i < 4; ++i) {
      float x[16];
      if (isf32) ld16<true >(io, (size_t)(row0 + row) * NHD + q4 * 64 + i * 16, x);
      else       ld16<false>(io, (size_t)(row0 + row) * NHD + q4 * 64 + i * 16, x);
      const int k16 = q4 * 8 + 2 * i;
#pragma unroll
      for (int j = 0; j < 2; ++j) {
        const int slot = (k16 + j) ^ (row & 7);
        uint4 pk = make_uint4(pk2(x[8*j+0], x[8*j+1]), pk2(x[8*j+2], x[8*j+3]),
                              pk2(x[8*j+4], x[8*j+5]), pk2(x[8*j+6], x[8*j+7]));
        *(uint4*)(As + (size_t)row * 256 + slot * 8) = pk;
      }
    }
  }
  __syncthreads();

  const f32x4 zero = {0.f, 0.f, 0.f, 0.f};
  for (int nt = 0; nt < 4; ++nt) {
    union { uint4 u; short8 s; } wf[8];
#pragma unroll
    for (int k8 = 0; k8 < 8; ++k8)
      wf[k8].u = *(const uint4*)(woT + (size_t)(w * 64 + nt * 16 + q15) * NC + k8 * 32 + g * 8);
#pragma unroll
    for (int ms = 0; ms < 4; ++ms) {
      const int mi = ms * 16 + q15;
      f32x4 acc = zero;
#pragma unroll
      for (int k8 = 0; k8 < 8; ++k8) {
        const int slot = (k8 * 4 + g) ^ (mi & 7);
        union { uint4 u; short8 s; } af;
        af.u = *(const uint4*)(As + (size_t)mi * 256 + slot * 8);
        acc = __builtin_amdgcn_mfma_f32_16x16x32_bf16(wf[k8].s, af.s, acc, 0, 0, 0);
      }
      const int n0l = w * 64 + nt * 16 + 4 * g;
      const int m = row0 + ms * 16 + q15;
      float v[4];
#pragma unroll
      for (int r = 0; r < 4; ++r) {
        float bov = isf32 ? ldE<true>(bo, n0l + r) : ldE<false>(bo, n0l + r);
        v[r] = acc[r] + bov;
      }
      if (isf32) {
        float4 st = make_float4(v[0], v[1], v[2], v[3]);
        *(float4*)((float*)io + (size_t)m * NC + n0l) = st;
      } else {
        uint2 pk; pk.x = pk2(v[0], v[1]); pk.y = pk2(v[2], v[3]);
        *(uint2*)((u16*)io + (size_t)m * NC + n0l) = pk;
      }
    }
  }
}

extern "C" void kernel_launch(void* const* d_in, const int* in_sizes, int n_in,
                              void* d_out, int out_size, void* d_ws, size_t ws_size,
                              hipStream_t stream) {
  const void* msa    = d_in[0];
  const void* gamma_ = d_in[1];
  const void* beta_  = d_in[2];
  const void* wq     = d_in[3];
  const void* wk     = d_in[4];
  const void* wv     = d_in[5];
  const void* wg     = d_in[6];
  const void* bg     = d_in[7];
  const void* wo     = d_in[8];
  const void* bo     = d_in[9];

  const size_t NE = (size_t)NS * NL * NH * ND;  // 25,165,824 elems
  int* flag = (int*)d_ws;
  u16* wT = (u16*)((char*)d_ws + 256);          // 5 x 65536 bf16 = 640 KB
  u16* qb = wT + 5 * 65536;
  u16* kb = qb + NE;
  u16* vb = kb + NE;
  u16* gb = vb + NE;

  k_probe<<<dim3(1), dim3(64), 0, stream>>>((const u16*)msa, flag);
  k_wt<<<dim3(80), dim3(256), 0, stream>>>(flag, wq, wk, wv, wg, wo, wT);
  k_proj<<<dim3(1536), dim3(256), 0, stream>>>(flag, msa, gamma_, beta_, bg, wT,
                                               qb, kb, vb, gb);
  k_attn<<<dim3(NL * NH), dim3(256), 0, stream>>>(flag, qb, kb, vb, gb, d_out);
  k_out<<<dim3(1536), dim3(256), 0, stream>>>(flag, d_out, wT + 4 * 65536, bo);
}

// Round 6
// 591.630 us; speedup vs baseline: 3.7530x; 1.0400x over previous
//
#include <hip/hip_runtime.h>
#include <hip/hip_bf16.h>
#include <stdint.h>

// Shapes
#define NS 256   // seq (attended axis)
#define NL 384   // columns
#define NC 256   // channel
#define NH 8     // heads
#define ND 32    // head dim
#define NHD 256  // NH*ND
#define NFQ 0.17677669529663687f  // 1/sqrt(32)

typedef unsigned short u16;
typedef unsigned int u32;
typedef __attribute__((ext_vector_type(8))) short short8;
typedef __attribute__((ext_vector_type(4))) float f32x4;

__device__ __forceinline__ float bf2f(u16 u) {
  union { u32 u; float f; } w; w.u = ((u32)u) << 16; return w.f;
}
__device__ __forceinline__ float lo16(u32 u) {
  union { u32 u; float f; } w; w.u = u << 16; return w.f;
}
__device__ __forceinline__ float hi16(u32 u) {
  union { u32 u; float f; } w; w.u = u & 0xffff0000u; return w.f;
}
__device__ __forceinline__ u16 f2bf_rne(float f) {
  u32 x = __float_as_uint(f);
  u32 lsb = (x >> 16) & 1u;
  x += 0x7fffu + lsb;
  return (u16)(x >> 16);
}
__device__ __forceinline__ u32 pk2(float a, float b) {
  return (u32)f2bf_rne(a) | ((u32)f2bf_rne(b) << 16);
}

// dtype-generic element load
template<bool F32>
__device__ __forceinline__ float ldE(const void* p, size_t i) {
  if constexpr (F32) return ((const float*)p)[i];
  else               return bf2f(((const u16*)p)[i]);
}
// dtype-generic 16-contiguous-element load (i must be multiple of 16)
template<bool F32>
__device__ __forceinline__ void ld16(const void* p, size_t i, float* x) {
  if constexpr (F32) {
    const float4* q = (const float4*)((const float*)p + i);
#pragma unroll
    for (int w = 0; w < 4; ++w) {
      float4 v = q[w];
      x[4*w] = v.x; x[4*w+1] = v.y; x[4*w+2] = v.z; x[4*w+3] = v.w;
    }
  } else {
    const uint4* q = (const uint4*)((const u16*)p + i);
#pragma unroll
    for (int w = 0; w < 2; ++w) {
      uint4 v = q[w];
      u32 uu[4] = {v.x, v.y, v.z, v.w};
#pragma unroll
      for (int pk = 0; pk < 4; ++pk) {
        x[8*w + 2*pk]     = lo16(uu[pk]);
        x[8*w + 2*pk + 1] = hi16(uu[pk]);
      }
    }
  }
}

// ---------------- dtype probe ----------------
__global__ void k_probe(const u16* __restrict__ msa, int* __restrict__ flag) {
  const int t = threadIdx.x;  // 64 threads
  int cnt = 0;
#pragma unroll
  for (int i = 0; i < 4; ++i) {
    u16 v = msa[t * 4 + i];
    int e = (v >> 7) & 0xFF;
    cnt += (e >= 100 && e <= 150) ? 1 : 0;
  }
#pragma unroll
  for (int m = 1; m < 64; m <<= 1) cnt += __shfl_xor(cnt, m, 64);
  if (t == 0) *flag = (cnt < 220) ? 1 : 0;  // 1 = fp32 buffers
}

// ---------------- k_wt: transpose+cast 5 weights to bf16 wT[n][k] ----------------
__launch_bounds__(256)
__global__ void k_wt(const int* __restrict__ flag,
                     const void* __restrict__ w0, const void* __restrict__ w1,
                     const void* __restrict__ w2, const void* __restrict__ w3,
                     const void* __restrict__ w4,
                     u16* __restrict__ wT) {
  __shared__ float f[64][65];
  const int b = blockIdx.x;
  const int widx = b >> 4, tile = b & 15;
  const int k0 = (tile >> 2) * 64, n0 = (tile & 3) * 64;
  const void* src = widx == 0 ? w0 : widx == 1 ? w1 : widx == 2 ? w2 : widx == 3 ? w3 : w4;
  u16* dst = wT + widx * 65536;
  const int t = threadIdx.x;
  const bool isf32 = (*flag != 0);

  {
    const int kr = t >> 2, nc = (t & 3) * 16;
    float x[16];
    if (isf32) ld16<true >(src, (size_t)(k0 + kr) * NHD + n0 + nc, x);
    else       ld16<false>(src, (size_t)(k0 + kr) * NHD + n0 + nc, x);
#pragma unroll
    for (int i = 0; i < 16; ++i) f[kr][nc + i] = x[i];
  }
  __syncthreads();
  {
    const int nr = t >> 2, kc = (t & 3) * 16;
    u32 pk[8];
#pragma unroll
    for (int i = 0; i < 8; ++i)
      pk[i] = pk2(f[kc + 2*i][nr], f[kc + 2*i + 1][nr]);
    uint4* dp = (uint4*)(dst + (size_t)(n0 + nr) * NC + k0 + kc);
    dp[0] = make_uint4(pk[0], pk[1], pk[2], pk[3]);
    dp[1] = make_uint4(pk[4], pk[5], pk[6], pk[7]);
  }
}

// ---------------- k_proj: fused LN + 4 projections via MFMA ----------------
__launch_bounds__(256)
__global__ void k_proj(const int* __restrict__ flag,
                       const void* __restrict__ msa,
                       const void* __restrict__ gamma_,
                       const void* __restrict__ beta_,
                       const void* __restrict__ bg,
                       const u16* __restrict__ wT,
                       u16* __restrict__ qb,
                       u16* __restrict__ kb,
                       u16* __restrict__ vb,
                       u16* __restrict__ gb) {
  __shared__ u16 As[64 * 256];  // 32 KB, 16B slot s' = s ^ (row&7)
  const int t = threadIdx.x;
  const int w = t >> 6;
  const int lane = t & 63;
  const int q15 = lane & 15;
  const int g = lane >> 4;
  const int row0 = blockIdx.x * 64;
  const int s = row0 / NL;
  const int l0 = row0 % NL;
  const bool isf32 = (*flag != 0);

#pragma unroll
  for (int p = 0; p < 4; ++p) {
    const int row = p * 16 + (t >> 4);
    const int sub = t & 15;
    float x[16];
    if (isf32) ld16<true >(msa, (size_t)(row0 + row) * NC + sub * 16, x);
    else       ld16<false>(msa, (size_t)(row0 + row) * NC + sub * 16, x);
    float sm = 0.f, ss = 0.f;
#pragma unroll
    for (int i = 0; i < 16; ++i) { sm += x[i]; ss += x[i] * x[i]; }
#pragma unroll
    for (int msk = 1; msk < 16; msk <<= 1) {
      sm += __shfl_xor(sm, msk, 64);
      ss += __shfl_xor(ss, msk, 64);
    }
    float mu  = sm * (1.0f / NC);
    float var = fmaxf(ss * (1.0f / NC) - mu * mu, 0.0f);
    float rs  = rsqrtf(var + 1e-5f);
    float y[16];
#pragma unroll
    for (int i = 0; i < 16; ++i) {
      float gm = isf32 ? ldE<true>(gamma_, sub * 16 + i) : ldE<false>(gamma_, sub * 16 + i);
      float be = isf32 ? ldE<true>(beta_,  sub * 16 + i) : ldE<false>(beta_,  sub * 16 + i);
      y[i] = (x[i] - mu) * rs * gm + be;
    }
#pragma unroll
    for (int j = 0; j < 2; ++j) {
      const int slot = (2 * sub + j) ^ (row & 7);
      uint4 pk = make_uint4(pk2(y[8*j+0], y[8*j+1]), pk2(y[8*j+2], y[8*j+3]),
                            pk2(y[8*j+4], y[8*j+5]), pk2(y[8*j+6], y[8*j+7]));
      *(uint4*)(As + (size_t)row * 256 + slot * 8) = pk;
    }
  }
  __syncthreads();

  const u16* wTw = wT + (size_t)w * 65536;
  const f32x4 zero = {0.f, 0.f, 0.f, 0.f};

  for (int nt = 0; nt < 16; ++nt) {
    union { uint4 u; short8 s; } wf[8];
#pragma unroll
    for (int k8 = 0; k8 < 8; ++k8)
      wf[k8].u = *(const uint4*)(wTw + (size_t)(nt * 16 + q15) * NC + k8 * 32 + g * 8);
#pragma unroll
    for (int ms = 0; ms < 4; ++ms) {
      const int mi = ms * 16 + q15;
      f32x4 acc = zero;
#pragma unroll
      for (int k8 = 0; k8 < 8; ++k8) {
        const int slot = (k8 * 4 + g) ^ (mi & 7);
        union { uint4 u; short8 s; } af;
        af.u = *(const uint4*)(As + (size_t)mi * 256 + slot * 8);
        acc = __builtin_amdgcn_mfma_f32_16x16x32_bf16(wf[k8].s, af.s, acc, 0, 0, 0);
      }
      const int nl0 = nt * 16 + 4 * g;
      const int hh = nl0 >> 5, dd = nl0 & 31;
      const int l = l0 + ms * 16 + q15;
      const size_t ob = ((size_t)(l * NH + hh) * NS + s) * ND + dd;
      uint2 pk;
      if (w == 0) {
        pk.x = pk2(acc[0] * NFQ, acc[1] * NFQ);
        pk.y = pk2(acc[2] * NFQ, acc[3] * NFQ);
        *(uint2*)(qb + ob) = pk;
      } else if (w == 1) {
        pk.x = pk2(acc[0], acc[1]); pk.y = pk2(acc[2], acc[3]);
        *(uint2*)(kb + ob) = pk;
      } else if (w == 2) {
        pk.x = pk2(acc[0], acc[1]); pk.y = pk2(acc[2], acc[3]);
        *(uint2*)(vb + ob) = pk;
      } else {
        float z[4];
#pragma unroll
        for (int r = 0; r < 4; ++r) {
          float bgl = isf32 ? ldE<true>(bg, nl0 + r) : ldE<false>(bg, nl0 + r);
          z[r] = 1.0f / (1.0f + __expf(-(acc[r] + bgl)));
        }
        pk.x = pk2(z[0], z[1]); pk.y = pk2(z[2], z[3]);
        *(uint2*)(gb + ob) = pk;
      }
    }
  }
}

// ---------------- k_attn: MFMA column attention, register-resident P ----------------
// 3072 blocks x 256 threads (4 waves); wave w owns q rows [64w, 64w+64).
// Swapped QK^T leaves lane (q15,g) holding P[q15][16jt+4g+r]. PV uses the
// slot-permutation pi(8g+j) = 32kc + 16*(j>=4) + 4g + (j&3) on BOTH operands:
// A-frag = lane's own packed P regs (no LDS, no shuffles); V-frag gathered
// once per wave in the same key order. One barrier total.
#define VSTRIDE 36  // Vs row pad: scalar gather 8-way -> 2-way (free)

__launch_bounds__(256)
__global__ void k_attn(const int* __restrict__ flag,
                       const u16* __restrict__ qb,
                       const u16* __restrict__ kb,
                       const u16* __restrict__ vb,
                       const u16* __restrict__ gb,
                       void* __restrict__ outp) {
  __shared__ u16 Ks[NS * ND];       // 16 KB, 16B slots swizzled: s' = s ^ ((key>>1)&3)
  __shared__ u16 Vs[NS * VSTRIDE];  // 18 KB, padded rows
  const int t = threadIdx.x;
  const int w = t >> 6;
  const int lane = t & 63;
  const int q15 = lane & 15;
  const int g = lane >> 4;
  const int bid = blockIdx.x;
  const int c = bid >> 3, h = bid & 7;
  const size_t base = (size_t)bid * (NS * ND);
  const bool isf32 = (*flag != 0);

  // stage K (swizzled slots) and V (padded rows, 8B writes for alignment)
  {
    const uint4* kg = (const uint4*)(kb + base);
    const uint4* vg = (const uint4*)(vb + base);
#pragma unroll
    for (int i = 0; i < 4; ++i) {
      const int u = t + 256 * i;          // uint4 index: key = u>>2, slot = u&3
      const int key = u >> 2, slot = u & 3;
      const int s2 = slot ^ ((key >> 1) & 3);
      *(uint4*)(Ks + key * ND + s2 * 8) = kg[u];
      uint4 vv = vg[u];
      *(uint2*)(Vs + key * VSTRIDE + slot * 8)     = make_uint2(vv.x, vv.y);
      *(uint2*)(Vs + key * VSTRIDE + slot * 8 + 4) = make_uint2(vv.z, vv.w);
    }
  }

  // Q fragments (B-operand of swapped QK^T)
  short8 qf[4];
  const int q0w = w * 64;
#pragma unroll
  for (int it = 0; it < 4; ++it) {
    union { uint4 u; short8 s; } cv;
    cv.u = *(const uint4*)(qb + base + (size_t)(q0w + it * 16 + q15) * ND + g * 8);
    qf[it] = cv.s;
  }
  __syncthreads();  // the only barrier

  // V fragments in pi key order: elem j -> key = 32kc + 16*(j>=4) + 4g + (j&3)
  short8 vf[2][8];
#pragma unroll
  for (int kc = 0; kc < 8; ++kc) {
#pragma unroll
    for (int dt = 0; dt < 2; ++dt) {
      union { u16 e[8]; short8 s; } cv;
#pragma unroll
      for (int j = 0; j < 4; ++j) {
        cv.e[j]     = Vs[(size_t)(kc * 32 + 4 * g + j) * VSTRIDE + dt * 16 + q15];
        cv.e[j + 4] = Vs[(size_t)(kc * 32 + 16 + 4 * g + j) * VSTRIDE + dt * 16 + q15];
      }
      vf[dt][kc] = cv.s;
    }
  }

  const f32x4 zero = {0.f, 0.f, 0.f, 0.f};

  for (int it = 0; it < 4; ++it) {
    // ---- QK^T (swapped): lane (q15,g) reg (jt,r) = S[key=16jt+4g+r][q=q15] ----
    f32x4 sc[16];
#pragma unroll
    for (int jt = 0; jt < 16; ++jt) {
      const int srow = jt * 16 + q15;
      const int s2 = g ^ ((srow >> 1) & 3);
      union { uint4 u; short8 s; } kf;
      kf.u = *(const uint4*)(Ks + (size_t)srow * ND + s2 * 8);
      sc[jt] = __builtin_amdgcn_mfma_f32_16x16x32_bf16(kf.s, qf[it], zero, 0, 0, 0);
    }
    // ---- exact softmax in-register (64 scores/lane + 2 shfl) ----
    float mx = sc[0][0];
#pragma unroll
    for (int jt = 0; jt < 16; ++jt)
#pragma unroll
      for (int r = 0; r < 4; ++r) mx = fmaxf(mx, sc[jt][r]);
    mx = fmaxf(mx, __shfl_xor(mx, 16, 64));
    mx = fmaxf(mx, __shfl_xor(mx, 32, 64));
    float sum = 0.f;
#pragma unroll
    for (int jt = 0; jt < 16; ++jt)
#pragma unroll
      for (int r = 0; r < 4; ++r) {
        float e = __expf(sc[jt][r] - mx);
        sc[jt][r] = e;
        sum += e;
      }
    sum += __shfl_xor(sum, 16, 64);
    sum += __shfl_xor(sum, 32, 64);
    const float inv = 1.0f / sum;

    // ---- pack normalized P to bf16 in-register ----
    u32 P0[16], P1[16];
#pragma unroll
    for (int jt = 0; jt < 16; ++jt) {
      P0[jt] = pk2(sc[jt][0] * inv, sc[jt][1] * inv);
      P1[jt] = pk2(sc[jt][2] * inv, sc[jt][3] * inv);
    }

    // ---- PV: A-frag = own registers (pi-permuted), B-frag = vf ----
    f32x4 o0 = zero, o1 = zero;
#pragma unroll
    for (int kc = 0; kc < 8; ++kc) {
      union { u32 w4[4]; short8 s; } pa;
      pa.w4[0] = P0[2 * kc];     pa.w4[1] = P1[2 * kc];
      pa.w4[2] = P0[2 * kc + 1]; pa.w4[3] = P1[2 * kc + 1];
      o0 = __builtin_amdgcn_mfma_f32_16x16x32_bf16(pa.s, vf[0][kc], o0, 0, 0, 0);
      o1 = __builtin_amdgcn_mfma_f32_16x16x32_bf16(pa.s, vf[1][kc], o1, 0, 0, 0);
    }

    // ---- epilogue: gate + store. lane: d = q15 (+16), q = it*16+4g+r ----
    const int qrow0 = q0w + it * 16 + 4 * g;
#pragma unroll
    for (int r = 0; r < 4; ++r) {
      const int s_idx = qrow0 + r;
      float g0 = bf2f(gb[base + (size_t)s_idx * ND + q15]);
      float g1 = bf2f(gb[base + (size_t)s_idx * ND + 16 + q15]);
      float r0 = o0[r] * g0;
      float r1 = o1[r] * g1;
      const size_t off = ((size_t)s_idx * NL + c) * NHD + h * ND;
      if (isf32) {
        ((float*)outp)[off + q15] = r0;
        ((float*)outp)[off + 16 + q15] = r1;
      } else {
        ((u16*)outp)[off + q15] = f2bf_rne(r0);
        ((u16*)outp)[off + 16 + q15] = f2bf_rne(r1);
      }
    }
  }
}

// ---------------- k_out: MFMA out-projection, in-place on d_out ----------------
__launch_bounds__(256)
__global__ void k_out(const int* __restrict__ flag,
                      void* __restrict__ io,
                      const u16* __restrict__ woT,
                      const void* __restrict__ bo) {
  __shared__ u16 As[64 * 256];  // 32 KB swizzled
  const int t = threadIdx.x;
  const int w = t >> 6;
  const int lane = t & 63;
  const int q15 = lane & 15;
  const int g = lane >> 4;
  const int row0 = blockIdx.x * 64;
  const bool isf32 = (*flag != 0);

  {
    const int row = t >> 2, q4 = t & 3;
#pragma unroll
    for (int i = 0; i < 4; ++i) {
      float x[16];
      if (isf32) ld16<true >(io, (size_t)(row0 + row) * NHD + q4 * 64 + i * 16, x);
      else       ld16<false>(io, (size_t)(row0 + row) * NHD + q4 * 64 + i * 16, x);
      const int k16 = q4 * 8 + 2 * i;
#pragma unroll
      for (int j = 0; j < 2; ++j) {
        const int slot = (k16 + j) ^ (row & 7);
        uint4 pk = make_uint4(pk2(x[8*j+0], x[8*j+1]), pk2(x[8*j+2], x[8*j+3]),
                              pk2(x[8*j+4], x[8*j+5]), pk2(x[8*j+6], x[8*j+7]));
        *(uint4*)(As + (size_t)row * 256 + slot * 8) = pk;
      }
    }
  }
  __syncthreads();

  const f32x4 zero = {0.f, 0.f, 0.f, 0.f};
  for (int nt = 0; nt < 4; ++nt) {
    union { uint4 u; short8 s; } wf[8];
#pragma unroll
    for (int k8 = 0; k8 < 8; ++k8)
      wf[k8].u = *(const uint4*)(woT + (size_t)(w * 64 + nt * 16 + q15) * NC + k8 * 32 + g * 8);
#pragma unroll
    for (int ms = 0; ms < 4; ++ms) {
      const int mi = ms * 16 + q15;
      f32x4 acc = zero;
#pragma unroll
      for (int k8 = 0; k8 < 8; ++k8) {
        const int slot = (k8 * 4 + g) ^ (mi & 7);
        union { uint4 u; short8 s; } af;
        af.u = *(const uint4*)(As + (size_t)mi * 256 + slot * 8);
        acc = __builtin_amdgcn_mfma_f32_16x16x32_bf16(wf[k8].s, af.s, acc, 0, 0, 0);
      }
      const int n0l = w * 64 + nt * 16 + 4 * g;
      const int m = row0 + ms * 16 + q15;
      float v[4];
#pragma unroll
      for (int r = 0; r < 4; ++r) {
        float bov = isf32 ? ldE<true>(bo, n0l + r) : ldE<false>(bo, n0l + r);
        v[r] = acc[r] + bov;
      }
      if (isf32) {
        float4 st = make_float4(v[0], v[1], v[2], v[3]);
        *(float4*)((float*)io + (size_t)m * NC + n0l) = st;
      } else {
        uint2 pk; pk.x = pk2(v[0], v[1]); pk.y = pk2(v[2], v[3]);
        *(uint2*)((u16*)io + (size_t)m * NC + n0l) = pk;
      }
    }
  }
}

extern "C" void kernel_launch(void* const* d_in, const int* in_sizes, int n_in,
                              void* d_out, int out_size, void* d_ws, size_t ws_size,
                              hipStream_t stream) {
  const void* msa    = d_in[0];
  const void* gamma_ = d_in[1];
  const void* beta_  = d_in[2];
  const void* wq     = d_in[3];
  const void* wk     = d_in[4];
  const void* wv     = d_in[5];
  const void* wg     = d_in[6];
  const void* bg     = d_in[7];
  const void* wo     = d_in[8];
  const void* bo     = d_in[9];

  const size_t NE = (size_t)NS * NL * NH * ND;  // 25,165,824 elems
  int* flag = (int*)d_ws;
  u16* wT = (u16*)((char*)d_ws + 256);          // 5 x 65536 bf16 = 640 KB
  u16* qb = wT + 5 * 65536;
  u16* kb = qb + NE;
  u16* vb = kb + NE;
  u16* gb = vb + NE;

  k_probe<<<dim3(1), dim3(64), 0, stream>>>((const u16*)msa, flag);
  k_wt<<<dim3(80), dim3(256), 0, stream>>>(flag, wq, wk, wv, wg, wo, wT);
  k_proj<<<dim3(1536), dim3(256), 0, stream>>>(flag, msa, gamma_, beta_, bg, wT,
                                               qb, kb, vb, gb);
  k_attn<<<dim3(NL * NH), dim3(256), 0, stream>>>(flag, qb, kb, vb, gb, d_out);
  k_out<<<dim3(1536), dim3(256), 0, stream>>>(flag, d_out, wT + 4 * 65536, bo);
}

// Round 7
// 497.443 us; speedup vs baseline: 4.4636x; 1.1893x over previous
//
#include <hip/hip_runtime.h>
#include <hip/hip_bf16.h>
#include <stdint.h>

// Shapes
#define NS 256   // seq (attended axis)
#define NL 384   // columns
#define NC 256   // channel
#define NH 8     // heads
#define ND 32    // head dim
#define NHD 256  // NH*ND
#define NFQ 0.17677669529663687f  // 1/sqrt(32)

typedef unsigned short u16;
typedef unsigned int u32;
typedef __attribute__((ext_vector_type(8))) short short8;
typedef __attribute__((ext_vector_type(4))) float f32x4;

__device__ __forceinline__ float bf2f(u16 u) {
  union { u32 u; float f; } w; w.u = ((u32)u) << 16; return w.f;
}
__device__ __forceinline__ float lo16(u32 u) {
  union { u32 u; float f; } w; w.u = u << 16; return w.f;
}
__device__ __forceinline__ float hi16(u32 u) {
  union { u32 u; float f; } w; w.u = u & 0xffff0000u; return w.f;
}
__device__ __forceinline__ u16 f2bf_rne(float f) {
  u32 x = __float_as_uint(f);
  u32 lsb = (x >> 16) & 1u;
  x += 0x7fffu + lsb;
  return (u16)(x >> 16);
}
__device__ __forceinline__ u32 pk2(float a, float b) {
  return (u32)f2bf_rne(a) | ((u32)f2bf_rne(b) << 16);
}

template<bool F32>
__device__ __forceinline__ float ldE(const void* p, size_t i) {
  if constexpr (F32) return ((const float*)p)[i];
  else               return bf2f(((const u16*)p)[i]);
}
template<bool F32>
__device__ __forceinline__ void ld16(const void* p, size_t i, float* x) {
  if constexpr (F32) {
    const float4* q = (const float4*)((const float*)p + i);
#pragma unroll
    for (int w = 0; w < 4; ++w) {
      float4 v = q[w];
      x[4*w] = v.x; x[4*w+1] = v.y; x[4*w+2] = v.z; x[4*w+3] = v.w;
    }
  } else {
    const uint4* q = (const uint4*)((const u16*)p + i);
#pragma unroll
    for (int w = 0; w < 2; ++w) {
      uint4 v = q[w];
      u32 uu[4] = {v.x, v.y, v.z, v.w};
#pragma unroll
      for (int pk = 0; pk < 4; ++pk) {
        x[8*w + 2*pk]     = lo16(uu[pk]);
        x[8*w + 2*pk + 1] = hi16(uu[pk]);
      }
    }
  }
}

// ---------------- dtype probe ----------------
__global__ void k_probe(const u16* __restrict__ msa, int* __restrict__ flag) {
  const int t = threadIdx.x;  // 64 threads
  int cnt = 0;
#pragma unroll
  for (int i = 0; i < 4; ++i) {
    u16 v = msa[t * 4 + i];
    int e = (v >> 7) & 0xFF;
    cnt += (e >= 100 && e <= 150) ? 1 : 0;
  }
#pragma unroll
  for (int m = 1; m < 64; m <<= 1) cnt += __shfl_xor(cnt, m, 64);
  if (t == 0) *flag = (cnt < 220) ? 1 : 0;  // 1 = fp32 buffers
}

// ---------------- k_wt: transpose+cast 5 weights to bf16 wT[n][k] ----------------
__launch_bounds__(256)
__global__ void k_wt(const int* __restrict__ flag,
                     const void* __restrict__ w0, const void* __restrict__ w1,
                     const void* __restrict__ w2, const void* __restrict__ w3,
                     const void* __restrict__ w4,
                     u16* __restrict__ wT) {
  __shared__ float f[64][65];
  const int b = blockIdx.x;
  const int widx = b >> 4, tile = b & 15;
  const int k0 = (tile >> 2) * 64, n0 = (tile & 3) * 64;
  const void* src = widx == 0 ? w0 : widx == 1 ? w1 : widx == 2 ? w2 : widx == 3 ? w3 : w4;
  u16* dst = wT + widx * 65536;
  const int t = threadIdx.x;
  const bool isf32 = (*flag != 0);

  {
    const int kr = t >> 2, nc = (t & 3) * 16;
    float x[16];
    if (isf32) ld16<true >(src, (size_t)(k0 + kr) * NHD + n0 + nc, x);
    else       ld16<false>(src, (size_t)(k0 + kr) * NHD + n0 + nc, x);
#pragma unroll
    for (int i = 0; i < 16; ++i) f[kr][nc + i] = x[i];
  }
  __syncthreads();
  {
    const int nr = t >> 2, kc = (t & 3) * 16;
    u32 pk[8];
#pragma unroll
    for (int i = 0; i < 8; ++i)
      pk[i] = pk2(f[kc + 2*i][nr], f[kc + 2*i + 1][nr]);
    uint4* dp = (uint4*)(dst + (size_t)(n0 + nr) * NC + k0 + kc);
    dp[0] = make_uint4(pk[0], pk[1], pk[2], pk[3]);
    dp[1] = make_uint4(pk[4], pk[5], pk[6], pk[7]);
  }
}

// ---------------- k_ln: LayerNorm -> bf16 mhat[m][256], coalesced ----------------
// 6144 blocks x 256 threads, 16 rows/block, 16 threads per row.
__launch_bounds__(256)
__global__ void k_ln(const int* __restrict__ flag,
                     const void* __restrict__ msa,
                     const void* __restrict__ gamma_,
                     const void* __restrict__ beta_,
                     u16* __restrict__ mh) {
  const int t = threadIdx.x;
  const int row = blockIdx.x * 16 + (t >> 4);
  const int sub = t & 15;
  const bool isf32 = (*flag != 0);
  float x[16];
  if (isf32) ld16<true >(msa, (size_t)row * NC + sub * 16, x);
  else       ld16<false>(msa, (size_t)row * NC + sub * 16, x);
  float sm = 0.f, ss = 0.f;
#pragma unroll
  for (int i = 0; i < 16; ++i) { sm += x[i]; ss += x[i] * x[i]; }
#pragma unroll
  for (int msk = 1; msk < 16; msk <<= 1) {
    sm += __shfl_xor(sm, msk, 64);
    ss += __shfl_xor(ss, msk, 64);
  }
  float mu  = sm * (1.0f / NC);
  float var = fmaxf(ss * (1.0f / NC) - mu * mu, 0.0f);
  float rs  = rsqrtf(var + 1e-5f);
  float y[16];
#pragma unroll
  for (int i = 0; i < 16; ++i) {
    float gm = isf32 ? ldE<true>(gamma_, sub * 16 + i) : ldE<false>(gamma_, sub * 16 + i);
    float be = isf32 ? ldE<true>(beta_,  sub * 16 + i) : ldE<false>(beta_,  sub * 16 + i);
    y[i] = (x[i] - mu) * rs * gm + be;
  }
  uint4* dp = (uint4*)(mh + (size_t)row * NC + sub * 16);
  dp[0] = make_uint4(pk2(y[0], y[1]),  pk2(y[2], y[3]),  pk2(y[4], y[5]),  pk2(y[6], y[7]));
  dp[1] = make_uint4(pk2(y[8], y[9]),  pk2(y[10], y[11]), pk2(y[12], y[13]), pk2(y[14], y[15]));
}

// ---------------- k_gemm<V>: 128x128-tile bf16 MFMA GEMM ----------------
// V=0: Y = mh @ [wq|wk|wv|wg] (N=1024), epilogue NFQ/sigmoid + scatter to
//      [L][H][S][D] buffers.  V=1: Y = xb @ wo + bo -> d_out [m][256].
// Block: 256 thr = 4 waves (2x2), wave = 64x64 tile (4x4 16x16 frags).
// K=256 in 4 chunks of BK=64; A/B tiles 16KB each, XOR-swizzled 16B slots.
template<int V>
__launch_bounds__(256)
__global__ void k_gemm(const int* __restrict__ flag,
                       const u16* __restrict__ Abuf,
                       const u16* __restrict__ Wbuf,
                       const void* __restrict__ bias,
                       u16* __restrict__ qb, u16* __restrict__ kb,
                       u16* __restrict__ vb, u16* __restrict__ gb,
                       void* __restrict__ outp) {
  __shared__ u16 Al[128 * 64];  // 16 KB, slot8' = slot8 ^ (row&7)
  __shared__ u16 Bl[128 * 64];  // 16 KB
  const int t = threadIdx.x;
  const int w = t >> 6, lane = t & 63;
  const int q15 = lane & 15, g = lane >> 4;
  const int wm = w >> 1, wn = w & 1;
  const int NB = (V == 0) ? 8 : 2;
  const int mb = blockIdx.x / NB, nb = blockIdx.x % NB;
  const int m0 = mb * 128, n0 = nb * 128;
  const bool isf32 = (*flag != 0);

  // staging addresses: thread t -> row srow (0..127), k-half shalf (32 elems)
  const int srow = t >> 1, shalf = t & 1;
  const u16* Ag = Abuf + (size_t)(m0 + srow) * NC + shalf * 32;
  const u16* Bg;
  if (V == 0) {
    const int ng = n0 + srow;  // global n 0..1023
    Bg = Wbuf + (size_t)(ng >> 8) * 65536 + (size_t)(ng & 255) * NC + shalf * 32;
  } else {
    Bg = Wbuf + (size_t)(n0 + srow) * NC + shalf * 32;
  }

  f32x4 acc[4][4];
#pragma unroll
  for (int i = 0; i < 4; ++i)
#pragma unroll
    for (int j = 0; j < 4; ++j) acc[i][j] = (f32x4){0.f, 0.f, 0.f, 0.f};

  for (int kc = 0; kc < 4; ++kc) {
    const uint4* av = (const uint4*)(Ag + kc * 64);
    const uint4* bv = (const uint4*)(Bg + kc * 64);
    uint4 ar[4], br[4];
#pragma unroll
    for (int u = 0; u < 4; ++u) { ar[u] = av[u]; br[u] = bv[u]; }
#pragma unroll
    for (int u = 0; u < 4; ++u) {
      const int slot = (shalf * 4 + u) ^ (srow & 7);
      *(uint4*)(Al + (size_t)srow * 64 + slot * 8) = ar[u];
      *(uint4*)(Bl + (size_t)srow * 64 + slot * 8) = br[u];
    }
    __syncthreads();
#pragma unroll
    for (int ks = 0; ks < 2; ++ks) {
      union { uint4 u; short8 s; } af[4], wf[4];
#pragma unroll
      for (int i = 0; i < 4; ++i) {
        const int rA = wm * 64 + i * 16 + q15;
        const int sA = (ks * 4 + g) ^ (rA & 7);
        af[i].u = *(const uint4*)(Al + (size_t)rA * 64 + sA * 8);
        const int rB = wn * 64 + i * 16 + q15;
        const int sB = (ks * 4 + g) ^ (rB & 7);
        wf[i].u = *(const uint4*)(Bl + (size_t)rB * 64 + sB * 8);
      }
#pragma unroll
      for (int mi = 0; mi < 4; ++mi)
#pragma unroll
        for (int ni = 0; ni < 4; ++ni)
          acc[mi][ni] = __builtin_amdgcn_mfma_f32_16x16x32_bf16(af[mi].s, wf[ni].s,
                                                               acc[mi][ni], 0, 0, 0);
    }
    __syncthreads();
  }

  // ---- epilogue. C-frag: col = q15 = n-local, row = 4g+r = m-local ----
#pragma unroll
  for (int mi = 0; mi < 4; ++mi) {
#pragma unroll
    for (int ni = 0; ni < 4; ++ni) {
      if constexpr (V == 0) {
        const int ngl = n0 + wn * 64 + ni * 16 + q15;   // 0..1023
        const int widx = ngl >> 8, nn = ngl & 255;
        const int hh = nn >> 5, dd = nn & 31;
        u16* dst = widx == 0 ? qb : widx == 1 ? kb : widx == 2 ? vb : gb;
        float bgv = 0.f;
        if (widx == 3) bgv = isf32 ? ldE<true>(bias, nn) : ldE<false>(bias, nn);
#pragma unroll
        for (int r = 0; r < 4; ++r) {
          const int m = m0 + wm * 64 + mi * 16 + 4 * g + r;
          const int s = m / NL, l = m % NL;
          float v = acc[mi][ni][r];
          if (widx == 0) v *= NFQ;
          if (widx == 3) v = 1.0f / (1.0f + __expf(-(v + bgv)));
          dst[((size_t)(l * NH + hh) * NS + s) * ND + dd] = f2bf_rne(v);
        }
      } else {
        const int n = n0 + wn * 64 + ni * 16 + q15;     // 0..255
        const float bov = isf32 ? ldE<true>(bias, n) : ldE<false>(bias, n);
#pragma unroll
        for (int r = 0; r < 4; ++r) {
          const int m = m0 + wm * 64 + mi * 16 + 4 * g + r;
          const float v = acc[mi][ni][r] + bov;
          if (isf32) ((float*)outp)[(size_t)m * NC + n] = v;
          else       ((u16*)outp)[(size_t)m * NC + n] = f2bf_rne(v);
        }
      }
    }
  }
}

// ---------------- k_attn: MFMA column attention, register-resident P ----------------
// (validated R6 structure; epilogue now writes bf16 to xb)
#define VSTRIDE 36

__launch_bounds__(256)
__global__ void k_attn(const u16* __restrict__ qb,
                       const u16* __restrict__ kb,
                       const u16* __restrict__ vb,
                       const u16* __restrict__ gb,
                       u16* __restrict__ xb) {
  __shared__ u16 Ks[NS * ND];       // 16 KB, slots swizzled: s' = s ^ ((key>>1)&3)
  __shared__ u16 Vs[NS * VSTRIDE];  // 18 KB, padded rows
  const int t = threadIdx.x;
  const int w = t >> 6;
  const int lane = t & 63;
  const int q15 = lane & 15;
  const int g = lane >> 4;
  const int bid = blockIdx.x;
  const int c = bid >> 3, h = bid & 7;
  const size_t base = (size_t)bid * (NS * ND);

  {
    const uint4* kg = (const uint4*)(kb + base);
    const uint4* vg = (const uint4*)(vb + base);
#pragma unroll
    for (int i = 0; i < 4; ++i) {
      const int u = t + 256 * i;
      const int key = u >> 2, slot = u & 3;
      const int s2 = slot ^ ((key >> 1) & 3);
      *(uint4*)(Ks + key * ND + s2 * 8) = kg[u];
      uint4 vv = vg[u];
      *(uint2*)(Vs + key * VSTRIDE + slot * 8)     = make_uint2(vv.x, vv.y);
      *(uint2*)(Vs + key * VSTRIDE + slot * 8 + 4) = make_uint2(vv.z, vv.w);
    }
  }

  short8 qf[4];
  const int q0w = w * 64;
#pragma unroll
  for (int it = 0; it < 4; ++it) {
    union { uint4 u; short8 s; } cv;
    cv.u = *(const uint4*)(qb + base + (size_t)(q0w + it * 16 + q15) * ND + g * 8);
    qf[it] = cv.s;
  }
  __syncthreads();

  short8 vf[2][8];
#pragma unroll
  for (int kc = 0; kc < 8; ++kc) {
#pragma unroll
    for (int dt = 0; dt < 2; ++dt) {
      union { u16 e[8]; short8 s; } cv;
#pragma unroll
      for (int j = 0; j < 4; ++j) {
        cv.e[j]     = Vs[(size_t)(kc * 32 + 4 * g + j) * VSTRIDE + dt * 16 + q15];
        cv.e[j + 4] = Vs[(size_t)(kc * 32 + 16 + 4 * g + j) * VSTRIDE + dt * 16 + q15];
      }
      vf[dt][kc] = cv.s;
    }
  }

  const f32x4 zero = {0.f, 0.f, 0.f, 0.f};

  for (int it = 0; it < 4; ++it) {
    f32x4 sc[16];
#pragma unroll
    for (int jt = 0; jt < 16; ++jt) {
      const int srow = jt * 16 + q15;
      const int s2 = g ^ ((srow >> 1) & 3);
      union { uint4 u; short8 s; } kf;
      kf.u = *(const uint4*)(Ks + (size_t)srow * ND + s2 * 8);
      sc[jt] = __builtin_amdgcn_mfma_f32_16x16x32_bf16(kf.s, qf[it], zero, 0, 0, 0);
    }
    float mx = sc[0][0];
#pragma unroll
    for (int jt = 0; jt < 16; ++jt)
#pragma unroll
      for (int r = 0; r < 4; ++r) mx = fmaxf(mx, sc[jt][r]);
    mx = fmaxf(mx, __shfl_xor(mx, 16, 64));
    mx = fmaxf(mx, __shfl_xor(mx, 32, 64));
    float sum = 0.f;
#pragma unroll
    for (int jt = 0; jt < 16; ++jt)
#pragma unroll
      for (int r = 0; r < 4; ++r) {
        float e = __expf(sc[jt][r] - mx);
        sc[jt][r] = e;
        sum += e;
      }
    sum += __shfl_xor(sum, 16, 64);
    sum += __shfl_xor(sum, 32, 64);
    const float inv = 1.0f / sum;

    u32 P0[16], P1[16];
#pragma unroll
    for (int jt = 0; jt < 16; ++jt) {
      P0[jt] = pk2(sc[jt][0] * inv, sc[jt][1] * inv);
      P1[jt] = pk2(sc[jt][2] * inv, sc[jt][3] * inv);
    }

    f32x4 o0 = zero, o1 = zero;
#pragma unroll
    for (int kc = 0; kc < 8; ++kc) {
      union { u32 w4[4]; short8 s; } pa;
      pa.w4[0] = P0[2 * kc];     pa.w4[1] = P1[2 * kc];
      pa.w4[2] = P0[2 * kc + 1]; pa.w4[3] = P1[2 * kc + 1];
      o0 = __builtin_amdgcn_mfma_f32_16x16x32_bf16(pa.s, vf[0][kc], o0, 0, 0, 0);
      o1 = __builtin_amdgcn_mfma_f32_16x16x32_bf16(pa.s, vf[1][kc], o1, 0, 0, 0);
    }

    const int qrow0 = q0w + it * 16 + 4 * g;
#pragma unroll
    for (int r = 0; r < 4; ++r) {
      const int s_idx = qrow0 + r;
      float g0 = bf2f(gb[base + (size_t)s_idx * ND + q15]);
      float g1 = bf2f(gb[base + (size_t)s_idx * ND + 16 + q15]);
      const size_t off = ((size_t)s_idx * NL + c) * NHD + h * ND;
      xb[off + q15]      = f2bf_rne(o0[r] * g0);
      xb[off + 16 + q15] = f2bf_rne(o1[r] * g1);
    }
  }
}

extern "C" void kernel_launch(void* const* d_in, const int* in_sizes, int n_in,
                              void* d_out, int out_size, void* d_ws, size_t ws_size,
                              hipStream_t stream) {
  const void* msa    = d_in[0];
  const void* gamma_ = d_in[1];
  const void* beta_  = d_in[2];
  const void* wq     = d_in[3];
  const void* wk     = d_in[4];
  const void* wv     = d_in[5];
  const void* wg     = d_in[6];
  const void* bg     = d_in[7];
  const void* wo     = d_in[8];
  const void* bo     = d_in[9];

  const size_t NE = (size_t)NS * NL * NH * ND;  // 25,165,824 elems (= 98304*256)
  int* flag = (int*)d_ws;
  u16* wT = (u16*)((char*)d_ws + 256);          // 5 x 65536 bf16 = 640 KB
  u16* qb = wT + 5 * 65536;
  u16* kb = qb + NE;
  u16* vb = kb + NE;
  u16* gb = vb + NE;
  u16* mh = gb + NE;                            // LN output, bf16 [m][256]
  u16* xb = mh + NE;                            // attn output, bf16 [m][256]

  k_probe<<<dim3(1), dim3(64), 0, stream>>>((const u16*)msa, flag);
  k_wt<<<dim3(80), dim3(256), 0, stream>>>(flag, wq, wk, wv, wg, wo, wT);
  k_ln<<<dim3(6144), dim3(256), 0, stream>>>(flag, msa, gamma_, beta_, mh);
  k_gemm<0><<<dim3(768 * 8), dim3(256), 0, stream>>>(flag, mh, wT, bg,
                                                     qb, kb, vb, gb, nullptr);
  k_attn<<<dim3(NL * NH), dim3(256), 0, stream>>>(qb, kb, vb, gb, xb);
  k_gemm<1><<<dim3(768 * 2), dim3(256), 0, stream>>>(flag, xb, wT + 4 * 65536, bo,
                                                     nullptr, nullptr, nullptr, nullptr, d_out);
}